// Round 15
// baseline (377.978 us; speedup 1.0000x reference)
//
#include <hip/hip_runtime.h>
#include <math.h>

#define Tn 128
#define Hn 128
#define Wn 128
#define Cn 32
#define NVOX (Tn*Hn*Wn)   // 2097152

typedef float4 f4;
typedef unsigned short ushort_t;
typedef __attribute__((ext_vector_type(8))) short short8;
typedef __attribute__((ext_vector_type(4))) float f32x4;
typedef __attribute__((ext_vector_type(2))) float f32x2;

// ---- bf16 pack/unpack (RNE) ----
__device__ __forceinline__ unsigned bfpack2(float a, float b) {
  unsigned ua = __float_as_uint(a), ub = __float_as_uint(b);
  ua = (ua + 0x7FFFu + ((ua >> 16) & 1u)) >> 16;
  ub = (ub + 0x7FFFu + ((ub >> 16) & 1u)) >> 16;
  return ua | (ub << 16);
}
__device__ __forceinline__ unsigned short bf1(float a) {
  unsigned u = __float_as_uint(a);
  u = (u + 0x7FFFu + ((u >> 16) & 1u)) >> 16;
  return (unsigned short)u;
}
__device__ __forceinline__ float bflo(unsigned p) { return __uint_as_float(p << 16); }
__device__ __forceinline__ float bfhi(unsigned p) { return __uint_as_float(p & 0xFFFF0000u); }
__device__ __forceinline__ float bfs(unsigned short s) { return __uint_as_float((unsigned)s << 16); }

// FORCED packed fp32 FMA: d = a * {b,b} + c  (one v_pk_fma_f32).
// Round-13 lesson: all VOP3P f32 sources must be 64-bit PAIRS — a single
// VGPR src1 does not assemble. b is wave-uniform at every call site
// (conv weights / tau_s), so {b,b} lives in an SGPR pair ("s" constraint,
// one scalar operand = within the constant-bus limit); the splat costs
// scalar-pipe s_movs only. NOTE: "s" on a divergent value would silently
// readfirstlane — only pass uniform b here.
__device__ __forceinline__ f32x2 pfma(f32x2 a, float b, f32x2 c) {
  f32x2 bb = {b, b};
  f32x2 d;
  asm("v_pk_fma_f32 %0, %1, %2, %3"
      : "=v"(d) : "v"(a), "s"(bb), "v"(c));
  return d;
}

union U4S8 { uint4 u; short8 s; };

// ===========================================================================
// Mh layout: 4 channel-quarter PLANES: Mh[j*NVOX + vox], j in [0,4), 16B each
// (quarter j = channels 8j..8j+7 packed bf16 in one uint4).
// Wave accesses are contiguous runs (8 full lines/inst) in every kernel.
// ===========================================================================

// ---------------------------------------------------------------------------
// convM: 1->32 conv, M [T,H,W] -> Mh planes. Thread pairs voxels (w, w+16).
// Forced-packed-f32 core. Fused X -> d_out copy.
// ---------------------------------------------------------------------------
__global__ __launch_bounds__(256) void k_convM(
    const float* __restrict__ M, const float* __restrict__ wM,
    uint4* __restrict__ Mh, const float* __restrict__ X,
    f4* __restrict__ outX)
{
  __shared__ float sm[1224];                      // 6*6*34
  const int w0 = blockIdx.x*32, h0 = blockIdx.y*4, t0 = blockIdx.z*4;
  const int tid = threadIdx.x;
  const bool interior = (w0 != 0) && (w0 != 96) && (h0 != 0) && (h0 != 124)
                     && (t0 != 0) && (t0 != 124);
  for (int idx = tid; idx < 1224; idx += 256) {
    int lw = idx % 34, r = idx / 34, lh = r % 6, ld = r / 6;
    int gw = w0 - 1 + lw, gh = h0 - 1 + lh, gt = t0 - 1 + ld;
    float v = 0.f;
    if (interior || ((unsigned)gw < Wn && (unsigned)gh < Hn && (unsigned)gt < Tn))
      v = M[((long)gt*Hn + gh)*Wn + gw];
    sm[idx] = v;
  }
  const int bid = (blockIdx.z*32 + blockIdx.y)*4 + blockIdx.x;
  if (tid < 128) outX[bid*128 + tid] = ((const f4*)X)[bid*128 + tid];
  __syncthreads();

  const int wp = tid & 15, th = (tid>>4)&3, td = tid>>6;
  f32x2 m2[27];
  #pragma unroll
  for (int kd = 0; kd < 3; ++kd)
    #pragma unroll
    for (int kh = 0; kh < 3; ++kh) {
      const float* row = &sm[(((td+kd)*6) + (th+kh))*34 + wp];
      int k0 = (kd*3 + kh)*3;
      m2[k0+0] = (f32x2){row[0], row[16]};
      m2[k0+1] = (f32x2){row[1], row[17]};
      m2[k0+2] = (f32x2){row[2], row[18]};
    }
  const long voxA = ((long)(t0+td)*Hn + (h0+th))*Wn + (w0+wp);
  #pragma unroll
  for (int j = 0; j < 4; ++j) {
    float rA[8], rB[8];
    #pragma unroll
    for (int e = 0; e < 8; ++e) {
      const int c = 8*j + e;
      f32x2 acc = {0.f, 0.f};
      #pragma unroll
      for (int k = 0; k < 27; ++k)
        acc = pfma(m2[k], wM[c*27 + k], acc);
      rA[e] = acc.x; rB[e] = acc.y;
    }
    uint4 oA, oB;
    oA.x = bfpack2(rA[0],rA[1]); oA.y = bfpack2(rA[2],rA[3]);
    oA.z = bfpack2(rA[4],rA[5]); oA.w = bfpack2(rA[6],rA[7]);
    oB.x = bfpack2(rB[0],rB[1]); oB.y = bfpack2(rB[2],rB[3]);
    oB.z = bfpack2(rB[4],rB[5]); oB.w = bfpack2(rB[6],rB[7]);
    Mh[(size_t)j*NVOX + voxA]      = oA;
    Mh[(size_t)j*NVOX + voxA + 16] = oB;
  }
}

// ---------------------------------------------------------------------------
// conv_fused v2: FULL-N MFMA. Wave output = 16w x 4h x 8t. B-matrix cols
// n = conv*8 + t_out; for plane p the column's weight is
// w_conv[kd = p - t_out][kh][kw] (zero outside [0,2]), read per-lane from a
// small LDS table. One 16x16 D per lh rolled over all 10 planes.
// MODE 0 = conv0+conv1, MODE 1 = conv4+sigmoid.
// ---------------------------------------------------------------------------
template<int MODE, int P>
__device__ __forceinline__ void plane_step(
    const uint4* __restrict__ SRC, const uint4* sBw,
    int tbase, int h0, int w0v, long lofs,
    int n, int kg, bool wL, bool wR, f32x4 (&acc)[4])
{
  const int gt = tbase - 1 + P;
  const bool tok = (unsigned)gt < Tn;
  U4S8 A[6][3];
  #pragma unroll
  for (int hr = 0; hr < 6; ++hr) {
    const int gh = h0 - 1 + hr;
    if (tok && (unsigned)gh < Hn) {
      const uint4* rowp = SRC + lofs + (((long)gt*Hn + gh)*Wn + (w0v - 1));
      A[hr][0].u = rowp[0];
      A[hr][1].u = rowp[1];
      A[hr][2].u = rowp[2];
    } else {
      A[hr][0].u = (uint4){0u,0u,0u,0u};
      A[hr][1].u = (uint4){0u,0u,0u,0u};
      A[hr][2].u = (uint4){0u,0u,0u,0u};
    }
  }
  if (wL && n == 0) {
    #pragma unroll
    for (int hr = 0; hr < 6; ++hr) A[hr][0].u = (uint4){0u,0u,0u,0u};
  }
  if (wR && n == 15) {
    #pragma unroll
    for (int hr = 0; hr < 6; ++hr) A[hr][2].u = (uint4){0u,0u,0u,0u};
  }
  __builtin_amdgcn_sched_barrier(0);

  const int kdl = P - (n & 7);
  int base;
  if constexpr (MODE == 0) {
    const int cv = n >> 3;
    base = ((unsigned)kdl <= 2u) ? ((cv*3 + kdl)*36 + kg) : (216 + kg);
  } else {
    base = (((unsigned)kdl <= 2u) && (n < 8)) ? (kdl*36 + kg) : (108 + kg);
  }
  const f32x4 fz = {0.f,0.f,0.f,0.f};
  #pragma unroll
  for (int t9 = 0; t9 < 9; ++t9) {
    const int kh = t9 / 3, kw = t9 % 3;
    U4S8 b; b.u = sBw[base + t9*4];
    const bool first = (P == 0 && t9 == 0);
    #pragma unroll
    for (int lh = 0; lh < 4; ++lh)
      acc[lh] = __builtin_amdgcn_mfma_f32_16x16x32_bf16(
          A[lh+kh][kw].s, b.s, first ? fz : acc[lh], 0, 0, 0);
  }
}

template<int MODE>
__global__ __launch_bounds__(256, 4) void k_conv_fused(
    const uint4* __restrict__ SRC, const float* __restrict__ wAp,
    const float* __restrict__ wBp, const float* __restrict__ bias_or_ms,
    ushort_t* __restrict__ outH, float* __restrict__ outF)
{
  __shared__ uint4 sBw[MODE == 0 ? 252 : 144];    // weights + zero pad
  const int tid = threadIdx.x;
  const int lane = tid & 63;
  const int n = lane & 15, kg = lane >> 4;

  if constexpr (MODE == 0) {
    for (int idx = tid; idx < 252; idx += 256) {
      uint4 v = {0u,0u,0u,0u};
      if (idx < 216) {
        int ckd = idx / 36, rem = idx % 36, t9 = rem >> 2, kgi = rem & 3;
        int conv = ckd / 3, kd = ckd % 3, tap = kd*9 + t9;
        const float* wp = conv ? wBp : wAp;
        v.x = bfpack2(wp[(kgi*8+0)*27+tap], wp[(kgi*8+1)*27+tap]);
        v.y = bfpack2(wp[(kgi*8+2)*27+tap], wp[(kgi*8+3)*27+tap]);
        v.z = bfpack2(wp[(kgi*8+4)*27+tap], wp[(kgi*8+5)*27+tap]);
        v.w = bfpack2(wp[(kgi*8+6)*27+tap], wp[(kgi*8+7)*27+tap]);
      }
      sBw[idx] = v;
    }
  } else {
    for (int idx = tid; idx < 144; idx += 256) {
      uint4 v = {0u,0u,0u,0u};
      if (idx < 108) {
        int kd = idx / 36, rem = idx % 36, t9 = rem >> 2, kgi = rem & 3;
        int tap = kd*9 + t9;
        v.x = bfpack2(wAp[(kgi*8+0)*27+tap], wAp[(kgi*8+1)*27+tap]);
        v.y = bfpack2(wAp[(kgi*8+2)*27+tap], wAp[(kgi*8+3)*27+tap]);
        v.z = bfpack2(wAp[(kgi*8+4)*27+tap], wAp[(kgi*8+5)*27+tap]);
        v.w = bfpack2(wAp[(kgi*8+6)*27+tap], wAp[(kgi*8+7)*27+tap]);
      }
      sBw[idx] = v;
    }
  }
  const float scal = bias_or_ms[0];   // MODE0: conv0 bias, MODE1: mask_scaling
  const int w0v = blockIdx.x*16, h0 = blockIdx.y*4;
  const int wv = __builtin_amdgcn_readfirstlane(tid >> 6);
  const int tbase = (blockIdx.z*4 + wv)*8;
  const long lofs = (long)kg*NVOX + n;             // plane offset + voxel lane
  const bool wL = (w0v == 0), wR = (w0v == Wn-16);
  __syncthreads();

  f32x4 acc[4];
  #define PS(P) plane_step<MODE,P>(SRC, sBw, tbase, h0, w0v, lofs, n, kg, wL, wR, acc);
  PS(0) PS(1) PS(2) PS(3) PS(4) PS(5) PS(6) PS(7) PS(8) PS(9)
  #undef PS

  // retire: D col n = (conv, t_out); rows = w = w0v + kg*4 + r
  const int tq = n & 7;
  const int tt = tbase + tq;
  if constexpr (MODE == 0) {
    if (n < 8) {                                   // conv0 -> bg2h
      #pragma unroll
      for (int lh = 0; lh < 4; ++lh) {
        const long vb = ((long)tt*Hn + (h0+lh))*Wn + w0v + kg*4;
        float q[4];
        #pragma unroll
        for (int r = 0; r < 4; ++r) {
          float bg = 1.f - fmaxf(acc[lh][r] + scal, 0.f);
          q[r] = bg*bg;
        }
        uint2 pk; pk.x = bfpack2(q[0],q[1]); pk.y = bfpack2(q[2],q[3]);
        *(uint2*)&outH[vb] = pk;
      }
    } else {                                       // conv1 -> c1m
      #pragma unroll
      for (int lh = 0; lh < 4; ++lh) {
        const long vb = ((long)tt*Hn + (h0+lh))*Wn + w0v + kg*4;
        f4 o;
        o.x = 1.f - acc[lh][0]; o.y = 1.f - acc[lh][1];
        o.z = 1.f - acc[lh][2]; o.w = 1.f - acc[lh][3];
        *(f4*)&outF[vb] = o;
      }
    }
  } else {
    if (n < 8) {                                   // conv4 + sigmoid -> Mout
      #pragma unroll
      for (int lh = 0; lh < 4; ++lh) {
        const long vb = ((long)tt*Hn + (h0+lh))*Wn + w0v + kg*4;
        f4 o;
        #pragma unroll
        for (int r = 0; r < 4; ++r) {
          float y = (acc[lh][r] - 0.5f)*scal;
          ((float*)&o)[r] = 1.f/(1.f + expf(-y));
        }
        *(f4*)&outF[vb] = o;
      }
    }
  }
}

// ---------------------------------------------------------------------------
// UV loop, linearized (first order in 1e-5 updates)
// ---------------------------------------------------------------------------
__global__ __launch_bounds__(512) void k_G(
    const float* __restrict__ X, const ushort_t* __restrict__ bg2h,
    const float* __restrict__ U0, const float* __restrict__ V0,
    float* __restrict__ G)
{
  __shared__ float Vs[128], Ucol[128], red[512];
  const int h = blockIdx.x;
  const int tid = threadIdx.x;
  const int w = tid & 127, tq = tid >> 7;
  if (tid < 128) Vs[tid] = V0[tid];
  else if (tid < 256) Ucol[tid-128] = U0[(tid-128)*128 + h];
  __syncthreads();
  const float vw = Vs[w];
  float acc = 0.f;
  const int tstart = tq*32;
  for (int t = tstart; t < tstart+32; ++t) {
    int idx = (t*Hn + h)*Wn + w;
    acc += bfs(bg2h[idx])*(X[idx] - Ucol[t]*vw)*Vs[t];
  }
  red[tid] = acc;
  __syncthreads();
  if (tq == 0)
    G[h*128 + w] = red[w] + red[128+w] + red[256+w] + red[384+w];
}

// out[t] = sum_hw T[t,hw] * D[hw]
__global__ __launch_bounds__(256) void k_dotT(
    const float* __restrict__ X, const ushort_t* __restrict__ bg2h,
    const float* __restrict__ U0, const float* __restrict__ V0,
    const float* __restrict__ D, float* __restrict__ out)
{
  __shared__ float Uc[128], Vs[128], red[256];
  const int t = blockIdx.x, tid = threadIdx.x;
  if (tid < 128) { Uc[tid] = U0[t*128 + tid]; Vs[tid] = V0[tid]; }
  __syncthreads();
  float acc = 0.f;
  for (int idx = tid; idx < 16384; idx += 256) {
    int h = idx >> 7, w = idx & 127;
    int gi = t*16384 + idx;
    acc += bfs(bg2h[gi])*(X[gi] - Uc[h]*Vs[w])*D[idx];
  }
  red[tid] = acc;
  __syncthreads();
  for (int s = 128; s > 0; s >>= 1) {
    if (tid < s) red[tid] += red[tid+s];
    __syncthreads();
  }
  if (tid == 0) out[t] = red[0];
}

__global__ __launch_bounds__(256) void k_final(
    const float* __restrict__ U0, const float* __restrict__ V0,
    const float* __restrict__ G, const float* __restrict__ u1,
    const float* __restrict__ g2, const float* __restrict__ ul,
    const float* __restrict__ vl,
    float* __restrict__ Ua, float* __restrict__ Va,
    float* __restrict__ outU, float* __restrict__ outV)
{
  const int tid = threadIdx.x;
  float A = 0.f, cu1 = 0.f, cg2 = 0.f;
  #pragma unroll
  for (int i = 0; i < 5; ++i) {
    float ai = 1e-5f*ul[i], bi = 1e-5f*vl[i];
    A += ai; cu1 += bi; cg2 += bi*A;
  }
  for (int idx = tid; idx < 16384; idx += 256) {
    float u = U0[idx] + A*G[idx];
    Ua[idx] = u; outU[idx] = u;
  }
  if (tid < 128) {
    float v = V0[tid] + cu1*u1[tid] + cg2*g2[tid];
    Va[tid] = v; outV[tid] = v;
  }
}

// ---------------------------------------------------------------------------
// k_z (plane layout + FORCED packed-f32 core): q inline in staging
// (q = c1m*(X-L)^2, L=U[h*128+w]*V[t]),
// z = softthresh(Mh + tau_s*conv2(q), g[c]*g2[h]*th[w]) in-place on Mh.
// ---------------------------------------------------------------------------
__global__ __launch_bounds__(256) void k_z(
    const float* __restrict__ X, const float* __restrict__ c1m,
    const float* __restrict__ Uf, const float* __restrict__ Vf,
    const float* __restrict__ w2, uint4* __restrict__ Mh,
    const float* __restrict__ taup, const float* __restrict__ g,
    const float* __restrict__ g2, const float* __restrict__ th)
{
  __shared__ float sm[1224];
  const int w0 = blockIdx.x*32, h0 = blockIdx.y*4, t0 = blockIdx.z*4;
  const int tid = threadIdx.x;
  const bool interior = (w0 != 0) && (w0 != 96) && (h0 != 0) && (h0 != 124)
                     && (t0 != 0) && (t0 != 124);
  for (int idx = tid; idx < 1224; idx += 256) {
    int lw = idx % 34, r = idx / 34, lh = r % 6, ld = r / 6;
    int gw = w0 - 1 + lw, gh = h0 - 1 + lh, gt = t0 - 1 + ld;
    float qv = 0.f;
    if (interior || ((unsigned)gw < Wn && (unsigned)gh < Hn && (unsigned)gt < Tn)) {
      long gi = ((long)gt*Hn + gh)*Wn + gw;
      float d = X[gi] - Uf[gh*Wn + gw]*Vf[gt];
      qv = c1m[gi]*d*d;
    }
    sm[idx] = qv;
  }
  __syncthreads();

  const float tau_s = log1pf(expf(taup[0]));      // softplus
  const int wp = tid & 15, thl = (tid>>4)&3, td = tid>>6;
  f32x2 m2[27];
  #pragma unroll
  for (int kd = 0; kd < 3; ++kd)
    #pragma unroll
    for (int kh = 0; kh < 3; ++kh) {
      const float* row = &sm[(((td+kd)*6) + (thl+kh))*34 + wp];
      int k0 = (kd*3 + kh)*3;
      m2[k0+0] = (f32x2){row[0], row[16]};
      m2[k0+1] = (f32x2){row[1], row[17]};
      m2[k0+2] = (f32x2){row[2], row[18]};
    }
  const int h = h0 + thl, wA = w0 + wp;
  const long voxA = ((long)(t0+td)*Hn + h)*Wn + wA;
  const float g2h = g2[h];
  const float thwA = g2h*th[wA], thwB = g2h*th[wA+16];

  #define ZJ(J)                                                             \
  {                                                                         \
    uint4 pA = Mh[(size_t)(J)*NVOX + voxA];                                 \
    uint4 pB = Mh[(size_t)(J)*NVOX + voxA + 16];                            \
    f32x2 in2[8] = {                                                        \
      {bflo(pA.x), bflo(pB.x)}, {bfhi(pA.x), bfhi(pB.x)},                   \
      {bflo(pA.y), bflo(pB.y)}, {bfhi(pA.y), bfhi(pB.y)},                   \
      {bflo(pA.z), bflo(pB.z)}, {bfhi(pA.z), bfhi(pB.z)},                   \
      {bflo(pA.w), bflo(pB.w)}, {bfhi(pA.w), bfhi(pB.w)}};                  \
    float oA[8], oB[8];                                                     \
    _Pragma("unroll")                                                       \
    for (int e = 0; e < 8; ++e) {                                           \
      const int c = 8*(J) + e;                                              \
      f32x2 acc = {0.f, 0.f};                                               \
      _Pragma("unroll")                                                     \
      for (int k = 0; k < 27; ++k)                                          \
        acc = pfma(m2[k], w2[c*27 + k], acc);                               \
      f32x2 rr = pfma(acc, tau_s, in2[e]);                                  \
      float gc = g[c];                                                      \
      float aA = fabsf(rr.x) - gc*thwA;                                     \
      float aB = fabsf(rr.y) - gc*thwB;                                     \
      oA[e] = (aA > 0.f) ? copysignf(aA, rr.x) : 0.f;                       \
      oB[e] = (aB > 0.f) ? copysignf(aB, rr.y) : 0.f;                       \
    }                                                                       \
    uint4 qA, qB;                                                           \
    qA.x = bfpack2(oA[0],oA[1]); qA.y = bfpack2(oA[2],oA[3]);               \
    qA.z = bfpack2(oA[4],oA[5]); qA.w = bfpack2(oA[6],oA[7]);               \
    qB.x = bfpack2(oB[0],oB[1]); qB.y = bfpack2(oB[2],oB[3]);               \
    qB.z = bfpack2(oB[4],oB[5]); qB.w = bfpack2(oB[6],oB[7]);               \
    Mh[(size_t)(J)*NVOX + voxA]      = qA;                                  \
    Mh[(size_t)(J)*NVOX + voxA + 16] = qB;                                  \
  }

  ZJ(0)
  ZJ(1)
  ZJ(2)
  ZJ(3)
  #undef ZJ
}

extern "C" void kernel_launch(void* const* d_in, const int* in_sizes, int n_in,
                              void* d_out, int out_size, void* d_ws, size_t ws_size,
                              hipStream_t stream)
{
  const float* X   = (const float*)d_in[0];
  const float* U0  = (const float*)d_in[1];
  const float* V0  = (const float*)d_in[2];
  const float* M   = (const float*)d_in[3];
  const float* wM  = (const float*)d_in[4];
  const float* w0  = (const float*)d_in[5];
  const float* b0  = (const float*)d_in[6];
  const float* w1  = (const float*)d_in[7];
  const float* w2  = (const float*)d_in[8];
  const float* w4  = (const float*)d_in[9];
  const float* tau = (const float*)d_in[10];
  const float* ms  = (const float*)d_in[11];
  const float* g   = (const float*)d_in[12];
  const float* th  = (const float*)d_in[13];
  const float* g2  = (const float*)d_in[14];
  const float* ul  = (const float*)d_in[15];
  const float* vl  = (const float*)d_in[16];

  // ws layout (Mh flanked by live ws memory; conv kernels may stray up to
  // 16B before/after the Mh planes at edges — those lanes are masked, reads
  // stay inside ws):  c1m fp32 8MB | Mh 4 planes bf16 134.2MB | bg2h 4MB | ...
  float*    c1m  = (float*)d_ws;
  uint4*    Mh   = (uint4*)((char*)d_ws + (size_t)NVOX*4);
  ushort_t* bg2h = (ushort_t*)((char*)Mh + (size_t)NVOX*64);
  float*    Ua   = (float*)((char*)bg2h + (size_t)NVOX*2);
  float*    Va   = Ua + 16384;
  float*    G    = Va + 128;
  float*    u1   = G + 16384;
  float*    g2v  = u1 + 128;

  float* out_f  = (float*)d_out;
  f4*    outX   = (f4*)d_out;                       // X at offset 0
  float* outU   = out_f + NVOX;                     // U after X
  float* outV   = outU + 16384;                     // V after U
  float* outM   = outV + 128;                       // M_out last

  k_convM <<<dim3(4,32,32), 256, 0, stream>>>(M, wM, Mh, X, outX);
  k_conv_fused<0><<<dim3(8,32,4), 256, 0, stream>>>(Mh, w0, w1, b0, bg2h, c1m);

  k_G    <<<128, 512, 0, stream>>>(X, bg2h, U0, V0, G);
  k_dotT <<<128, 256, 0, stream>>>(X, bg2h, U0, V0, U0, u1);
  k_dotT <<<128, 256, 0, stream>>>(X, bg2h, U0, V0, G, g2v);
  k_final<<<1, 256, 0, stream>>>(U0, V0, G, u1, g2v, ul, vl, Ua, Va, outU, outV);

  k_z    <<<dim3(4,32,32), 256, 0, stream>>>(X, c1m, Ua, Va, w2, Mh,
                                             tau, g, g2, th);
  k_conv_fused<1><<<dim3(8,32,4), 256, 0, stream>>>(Mh, w4, w4, ms, nullptr, outM);
}

// Round 16
// 361.758 us; speedup vs baseline: 1.0448x; 1.0448x over previous
//
#include <hip/hip_runtime.h>
#include <math.h>

#define Tn 128
#define Hn 128
#define Wn 128
#define Cn 32
#define NVOX (Tn*Hn*Wn)   // 2097152

typedef float4 f4;
typedef unsigned short ushort_t;
typedef __attribute__((ext_vector_type(8))) short short8;
typedef __attribute__((ext_vector_type(4))) float f32x4;
typedef __attribute__((ext_vector_type(2))) float f32x2;

// ---- bf16 pack/unpack (RNE) ----
__device__ __forceinline__ unsigned bfpack2(float a, float b) {
  unsigned ua = __float_as_uint(a), ub = __float_as_uint(b);
  ua = (ua + 0x7FFFu + ((ua >> 16) & 1u)) >> 16;
  ub = (ub + 0x7FFFu + ((ub >> 16) & 1u)) >> 16;
  return ua | (ub << 16);
}
__device__ __forceinline__ unsigned short bf1(float a) {
  unsigned u = __float_as_uint(a);
  u = (u + 0x7FFFu + ((u >> 16) & 1u)) >> 16;
  return (unsigned short)u;
}
__device__ __forceinline__ float bflo(unsigned p) { return __uint_as_float(p << 16); }
__device__ __forceinline__ float bfhi(unsigned p) { return __uint_as_float(p & 0xFFFF0000u); }
__device__ __forceinline__ float bfs(unsigned short s) { return __uint_as_float((unsigned)s << 16); }

// packed-f32 helper (round-15 lesson: gfx950 has NO double-rate packed FP32 —
// v_pk_fma_f32 issues at the same FLOP rate; forcing it regressed 9us. Keep
// the elementwise form and let the compiler pick.)
__device__ __forceinline__ f32x2 pfma(f32x2 a, float b, f32x2 c) {
  f32x2 bb = {b, b};
  return __builtin_elementwise_fma(a, bb, c);
}

union U4S8 { uint4 u; short8 s; };

// ===========================================================================
// Mh layout: 4 channel-quarter PLANES: Mh[j*NVOX + vox], j in [0,4), 16B each
// (quarter j = channels 8j..8j+7 packed bf16 in one uint4).
// Wave accesses are contiguous runs (8 full lines/inst) in every kernel.
// ===========================================================================

// ---------------------------------------------------------------------------
// convM: 1->32 conv, M [T,H,W] -> Mh planes. Thread pairs voxels (w, w+16).
// Fused X -> d_out copy.
// ---------------------------------------------------------------------------
__global__ __launch_bounds__(256) void k_convM(
    const float* __restrict__ M, const float* __restrict__ wM,
    uint4* __restrict__ Mh, const float* __restrict__ X,
    f4* __restrict__ outX)
{
  __shared__ float sm[1224];                      // 6*6*34
  const int w0 = blockIdx.x*32, h0 = blockIdx.y*4, t0 = blockIdx.z*4;
  const int tid = threadIdx.x;
  const bool interior = (w0 != 0) && (w0 != 96) && (h0 != 0) && (h0 != 124)
                     && (t0 != 0) && (t0 != 124);
  for (int idx = tid; idx < 1224; idx += 256) {
    int lw = idx % 34, r = idx / 34, lh = r % 6, ld = r / 6;
    int gw = w0 - 1 + lw, gh = h0 - 1 + lh, gt = t0 - 1 + ld;
    float v = 0.f;
    if (interior || ((unsigned)gw < Wn && (unsigned)gh < Hn && (unsigned)gt < Tn))
      v = M[((long)gt*Hn + gh)*Wn + gw];
    sm[idx] = v;
  }
  const int bid = (blockIdx.z*32 + blockIdx.y)*4 + blockIdx.x;
  if (tid < 128) outX[bid*128 + tid] = ((const f4*)X)[bid*128 + tid];
  __syncthreads();

  const int wp = tid & 15, th = (tid>>4)&3, td = tid>>6;
  f32x2 m2[27];
  #pragma unroll
  for (int kd = 0; kd < 3; ++kd)
    #pragma unroll
    for (int kh = 0; kh < 3; ++kh) {
      const float* row = &sm[(((td+kd)*6) + (th+kh))*34 + wp];
      int k0 = (kd*3 + kh)*3;
      m2[k0+0] = (f32x2){row[0], row[16]};
      m2[k0+1] = (f32x2){row[1], row[17]};
      m2[k0+2] = (f32x2){row[2], row[18]};
    }
  const long voxA = ((long)(t0+td)*Hn + (h0+th))*Wn + (w0+wp);
  #pragma unroll
  for (int j = 0; j < 4; ++j) {
    float rA[8], rB[8];
    #pragma unroll
    for (int e = 0; e < 8; ++e) {
      const int c = 8*j + e;
      f32x2 acc = {0.f, 0.f};
      #pragma unroll
      for (int k = 0; k < 27; ++k)
        acc = pfma(m2[k], wM[c*27 + k], acc);
      rA[e] = acc.x; rB[e] = acc.y;
    }
    uint4 oA, oB;
    oA.x = bfpack2(rA[0],rA[1]); oA.y = bfpack2(rA[2],rA[3]);
    oA.z = bfpack2(rA[4],rA[5]); oA.w = bfpack2(rA[6],rA[7]);
    oB.x = bfpack2(rB[0],rB[1]); oB.y = bfpack2(rB[2],rB[3]);
    oB.z = bfpack2(rB[4],rB[5]); oB.w = bfpack2(rB[6],rB[7]);
    Mh[(size_t)j*NVOX + voxA]      = oA;
    Mh[(size_t)j*NVOX + voxA + 16] = oB;
  }
}

// ---------------------------------------------------------------------------
// conv_fused v2: FULL-N MFMA. Wave output = 16w x 4h x 8t. B-matrix cols
// n = conv*8 + t_out; for plane p the column's weight is
// w_conv[kd = p - t_out][kh][kw] (zero outside [0,2]), read per-lane from a
// small LDS table. One 16x16 D per lh rolled over all 10 planes.
// MODE 0 = conv0+conv1, MODE 1 = conv4+sigmoid.
// ---------------------------------------------------------------------------
template<int MODE, int P>
__device__ __forceinline__ void plane_step(
    const uint4* __restrict__ SRC, const uint4* sBw,
    int tbase, int h0, int w0v, long lofs,
    int n, int kg, bool wL, bool wR, f32x4 (&acc)[4])
{
  const int gt = tbase - 1 + P;
  const bool tok = (unsigned)gt < Tn;
  U4S8 A[6][3];
  #pragma unroll
  for (int hr = 0; hr < 6; ++hr) {
    const int gh = h0 - 1 + hr;
    if (tok && (unsigned)gh < Hn) {
      const uint4* rowp = SRC + lofs + (((long)gt*Hn + gh)*Wn + (w0v - 1));
      A[hr][0].u = rowp[0];
      A[hr][1].u = rowp[1];
      A[hr][2].u = rowp[2];
    } else {
      A[hr][0].u = (uint4){0u,0u,0u,0u};
      A[hr][1].u = (uint4){0u,0u,0u,0u};
      A[hr][2].u = (uint4){0u,0u,0u,0u};
    }
  }
  if (wL && n == 0) {
    #pragma unroll
    for (int hr = 0; hr < 6; ++hr) A[hr][0].u = (uint4){0u,0u,0u,0u};
  }
  if (wR && n == 15) {
    #pragma unroll
    for (int hr = 0; hr < 6; ++hr) A[hr][2].u = (uint4){0u,0u,0u,0u};
  }
  __builtin_amdgcn_sched_barrier(0);

  const int kdl = P - (n & 7);
  int base;
  if constexpr (MODE == 0) {
    const int cv = n >> 3;
    base = ((unsigned)kdl <= 2u) ? ((cv*3 + kdl)*36 + kg) : (216 + kg);
  } else {
    base = (((unsigned)kdl <= 2u) && (n < 8)) ? (kdl*36 + kg) : (108 + kg);
  }
  const f32x4 fz = {0.f,0.f,0.f,0.f};
  #pragma unroll
  for (int t9 = 0; t9 < 9; ++t9) {
    const int kh = t9 / 3, kw = t9 % 3;
    U4S8 b; b.u = sBw[base + t9*4];
    const bool first = (P == 0 && t9 == 0);
    #pragma unroll
    for (int lh = 0; lh < 4; ++lh)
      acc[lh] = __builtin_amdgcn_mfma_f32_16x16x32_bf16(
          A[lh+kh][kw].s, b.s, first ? fz : acc[lh], 0, 0, 0);
  }
}

template<int MODE>
__global__ __launch_bounds__(256, 4) void k_conv_fused(
    const uint4* __restrict__ SRC, const float* __restrict__ wAp,
    const float* __restrict__ wBp, const float* __restrict__ bias_or_ms,
    ushort_t* __restrict__ outH, float* __restrict__ outF)
{
  __shared__ uint4 sBw[MODE == 0 ? 252 : 144];    // weights + zero pad
  const int tid = threadIdx.x;
  const int lane = tid & 63;
  const int n = lane & 15, kg = lane >> 4;

  if constexpr (MODE == 0) {
    for (int idx = tid; idx < 252; idx += 256) {
      uint4 v = {0u,0u,0u,0u};
      if (idx < 216) {
        int ckd = idx / 36, rem = idx % 36, t9 = rem >> 2, kgi = rem & 3;
        int conv = ckd / 3, kd = ckd % 3, tap = kd*9 + t9;
        const float* wp = conv ? wBp : wAp;
        v.x = bfpack2(wp[(kgi*8+0)*27+tap], wp[(kgi*8+1)*27+tap]);
        v.y = bfpack2(wp[(kgi*8+2)*27+tap], wp[(kgi*8+3)*27+tap]);
        v.z = bfpack2(wp[(kgi*8+4)*27+tap], wp[(kgi*8+5)*27+tap]);
        v.w = bfpack2(wp[(kgi*8+6)*27+tap], wp[(kgi*8+7)*27+tap]);
      }
      sBw[idx] = v;
    }
  } else {
    for (int idx = tid; idx < 144; idx += 256) {
      uint4 v = {0u,0u,0u,0u};
      if (idx < 108) {
        int kd = idx / 36, rem = idx % 36, t9 = rem >> 2, kgi = rem & 3;
        int tap = kd*9 + t9;
        v.x = bfpack2(wAp[(kgi*8+0)*27+tap], wAp[(kgi*8+1)*27+tap]);
        v.y = bfpack2(wAp[(kgi*8+2)*27+tap], wAp[(kgi*8+3)*27+tap]);
        v.z = bfpack2(wAp[(kgi*8+4)*27+tap], wAp[(kgi*8+5)*27+tap]);
        v.w = bfpack2(wAp[(kgi*8+6)*27+tap], wAp[(kgi*8+7)*27+tap]);
      }
      sBw[idx] = v;
    }
  }
  const float scal = bias_or_ms[0];   // MODE0: conv0 bias, MODE1: mask_scaling
  const int w0v = blockIdx.x*16, h0 = blockIdx.y*4;
  const int wv = __builtin_amdgcn_readfirstlane(tid >> 6);
  const int tbase = (blockIdx.z*4 + wv)*8;
  const long lofs = (long)kg*NVOX + n;             // plane offset + voxel lane
  const bool wL = (w0v == 0), wR = (w0v == Wn-16);
  __syncthreads();

  f32x4 acc[4];
  #define PS(P) plane_step<MODE,P>(SRC, sBw, tbase, h0, w0v, lofs, n, kg, wL, wR, acc);
  PS(0) PS(1) PS(2) PS(3) PS(4) PS(5) PS(6) PS(7) PS(8) PS(9)
  #undef PS

  // retire: D col n = (conv, t_out); rows = w = w0v + kg*4 + r
  const int tq = n & 7;
  const int tt = tbase + tq;
  if constexpr (MODE == 0) {
    if (n < 8) {                                   // conv0 -> bg2h
      #pragma unroll
      for (int lh = 0; lh < 4; ++lh) {
        const long vb = ((long)tt*Hn + (h0+lh))*Wn + w0v + kg*4;
        float q[4];
        #pragma unroll
        for (int r = 0; r < 4; ++r) {
          float bg = 1.f - fmaxf(acc[lh][r] + scal, 0.f);
          q[r] = bg*bg;
        }
        uint2 pk; pk.x = bfpack2(q[0],q[1]); pk.y = bfpack2(q[2],q[3]);
        *(uint2*)&outH[vb] = pk;
      }
    } else {                                       // conv1 -> c1m
      #pragma unroll
      for (int lh = 0; lh < 4; ++lh) {
        const long vb = ((long)tt*Hn + (h0+lh))*Wn + w0v + kg*4;
        f4 o;
        o.x = 1.f - acc[lh][0]; o.y = 1.f - acc[lh][1];
        o.z = 1.f - acc[lh][2]; o.w = 1.f - acc[lh][3];
        *(f4*)&outF[vb] = o;
      }
    }
  } else {
    if (n < 8) {                                   // conv4 + sigmoid -> Mout
      #pragma unroll
      for (int lh = 0; lh < 4; ++lh) {
        const long vb = ((long)tt*Hn + (h0+lh))*Wn + w0v + kg*4;
        f4 o;
        #pragma unroll
        for (int r = 0; r < 4; ++r) {
          float y = (acc[lh][r] - 0.5f)*scal;
          ((float*)&o)[r] = 1.f/(1.f + expf(-y));
        }
        *(f4*)&outF[vb] = o;
      }
    }
  }
}

// ---------------------------------------------------------------------------
// UV loop, linearized. PARALLELIZED: each reduction split into 4 partial
// blocks (grid (128,4) = 512 blocks, ~2/CU) with partials in ws; consumers
// (k_dotT<1>, k_final) fold the 4-way sums inline. No atomics, no zeroing.
// ---------------------------------------------------------------------------
__global__ __launch_bounds__(256) void k_G(
    const float* __restrict__ X, const ushort_t* __restrict__ bg2h,
    const float* __restrict__ U0, const float* __restrict__ V0,
    float* __restrict__ Gp)
{
  __shared__ float Vs[128], Ucol[32], red[256];
  const int h = blockIdx.x, tc = blockIdx.y;
  const int tid = threadIdx.x;
  const int w = tid & 127, half = tid >> 7;
  if (tid < 128) Vs[tid] = V0[tid];
  else if (tid < 160) Ucol[tid-128] = U0[(tc*32 + (tid-128))*128 + h];
  __syncthreads();
  const float vw = Vs[w];
  float acc = 0.f;
  const int tstart = tc*32 + half*16;
  for (int i = 0; i < 16; ++i) {
    int t = tstart + i;
    int idx = (t*Hn + h)*Wn + w;
    acc += bfs(bg2h[idx])*(X[idx] - Ucol[t - tc*32]*vw)*Vs[t];
  }
  red[tid] = acc;
  __syncthreads();
  if (half == 0)
    Gp[tc*16384 + h*128 + w] = red[w] + red[128+w];
}

// outp[hc*128+t] = sum over hw-chunk hc of T[t,hw]*D[hw].
// GS=1: D points at 4 G-partials; sum them inline.
template<int GS>
__global__ __launch_bounds__(256) void k_dotT(
    const float* __restrict__ X, const ushort_t* __restrict__ bg2h,
    const float* __restrict__ U0, const float* __restrict__ V0,
    const float* __restrict__ D, float* __restrict__ outp)
{
  __shared__ float Uc[128], Vs[128], red[256];
  const int t = blockIdx.x, hc = blockIdx.y, tid = threadIdx.x;
  if (tid < 128) { Uc[tid] = U0[t*128 + tid]; Vs[tid] = V0[tid]; }
  __syncthreads();
  float acc = 0.f;
  const int base = hc*4096;
  for (int k = 0; k < 16; ++k) {
    int idx = base + k*256 + tid;
    int h = idx >> 7, w = idx & 127;
    int gi = t*16384 + idx;
    float d;
    if constexpr (GS)
      d = D[idx] + D[16384+idx] + D[32768+idx] + D[49152+idx];
    else
      d = D[idx];
    acc += bfs(bg2h[gi])*(X[gi] - Uc[h]*Vs[w])*d;
  }
  red[tid] = acc;
  __syncthreads();
  for (int s = 128; s > 0; s >>= 1) {
    if (tid < s) red[tid] += red[tid+s];
    __syncthreads();
  }
  if (tid == 0) outp[hc*128 + t] = red[0];
}

__global__ __launch_bounds__(256) void k_final(
    const float* __restrict__ U0, const float* __restrict__ V0,
    const float* __restrict__ Gp, const float* __restrict__ u1p,
    const float* __restrict__ g2p, const float* __restrict__ ul,
    const float* __restrict__ vl,
    float* __restrict__ Ua, float* __restrict__ Va,
    float* __restrict__ outU, float* __restrict__ outV)
{
  const int tid = threadIdx.x;
  float A = 0.f, cu1 = 0.f, cg2 = 0.f;
  #pragma unroll
  for (int i = 0; i < 5; ++i) {
    float ai = 1e-5f*ul[i], bi = 1e-5f*vl[i];
    A += ai; cu1 += bi; cg2 += bi*A;
  }
  for (int idx = tid; idx < 16384; idx += 256) {
    float Gs = Gp[idx] + Gp[16384+idx] + Gp[32768+idx] + Gp[49152+idx];
    float u = U0[idx] + A*Gs;
    Ua[idx] = u; outU[idx] = u;
  }
  if (tid < 128) {
    float u1 = u1p[tid] + u1p[128+tid] + u1p[256+tid] + u1p[384+tid];
    float g2 = g2p[tid] + g2p[128+tid] + g2p[256+tid] + g2p[384+tid];
    float v = V0[tid] + cu1*u1 + cg2*g2;
    Va[tid] = v; outV[tid] = v;
  }
}

// ---------------------------------------------------------------------------
// k_z (plane layout, round-12 core): q inline in staging
// (q = c1m*(X-L)^2, L=U[h*128+w]*V[t]),
// z = softthresh(Mh + tau_s*conv2(q), g[c]*g2[h]*th[w]) in-place on Mh.
// ---------------------------------------------------------------------------
__global__ __launch_bounds__(256) void k_z(
    const float* __restrict__ X, const float* __restrict__ c1m,
    const float* __restrict__ Uf, const float* __restrict__ Vf,
    const float* __restrict__ w2, uint4* __restrict__ Mh,
    const float* __restrict__ taup, const float* __restrict__ g,
    const float* __restrict__ g2, const float* __restrict__ th)
{
  __shared__ float sm[1224];
  const int w0 = blockIdx.x*32, h0 = blockIdx.y*4, t0 = blockIdx.z*4;
  const int tid = threadIdx.x;
  const bool interior = (w0 != 0) && (w0 != 96) && (h0 != 0) && (h0 != 124)
                     && (t0 != 0) && (t0 != 124);
  for (int idx = tid; idx < 1224; idx += 256) {
    int lw = idx % 34, r = idx / 34, lh = r % 6, ld = r / 6;
    int gw = w0 - 1 + lw, gh = h0 - 1 + lh, gt = t0 - 1 + ld;
    float qv = 0.f;
    if (interior || ((unsigned)gw < Wn && (unsigned)gh < Hn && (unsigned)gt < Tn)) {
      long gi = ((long)gt*Hn + gh)*Wn + gw;
      float d = X[gi] - Uf[gh*Wn + gw]*Vf[gt];
      qv = c1m[gi]*d*d;
    }
    sm[idx] = qv;
  }
  __syncthreads();

  const float tau_s = log1pf(expf(taup[0]));      // softplus
  const int wp = tid & 15, thl = (tid>>4)&3, td = tid>>6;
  f32x2 m2[27];
  #pragma unroll
  for (int kd = 0; kd < 3; ++kd)
    #pragma unroll
    for (int kh = 0; kh < 3; ++kh) {
      const float* row = &sm[(((td+kd)*6) + (thl+kh))*34 + wp];
      int k0 = (kd*3 + kh)*3;
      m2[k0+0] = (f32x2){row[0], row[16]};
      m2[k0+1] = (f32x2){row[1], row[17]};
      m2[k0+2] = (f32x2){row[2], row[18]};
    }
  const int h = h0 + thl, wA = w0 + wp;
  const long voxA = ((long)(t0+td)*Hn + h)*Wn + wA;
  const float g2h = g2[h];
  const float thwA = g2h*th[wA], thwB = g2h*th[wA+16];

  #define ZJ(J)                                                             \
  {                                                                         \
    uint4 pA = Mh[(size_t)(J)*NVOX + voxA];                                 \
    uint4 pB = Mh[(size_t)(J)*NVOX + voxA + 16];                            \
    f32x2 in2[8] = {                                                        \
      {bflo(pA.x), bflo(pB.x)}, {bfhi(pA.x), bfhi(pB.x)},                   \
      {bflo(pA.y), bflo(pB.y)}, {bfhi(pA.y), bfhi(pB.y)},                   \
      {bflo(pA.z), bflo(pB.z)}, {bfhi(pA.z), bfhi(pB.z)},                   \
      {bflo(pA.w), bflo(pB.w)}, {bfhi(pA.w), bfhi(pB.w)}};                  \
    float oA[8], oB[8];                                                     \
    _Pragma("unroll")                                                       \
    for (int e = 0; e < 8; ++e) {                                           \
      const int c = 8*(J) + e;                                              \
      f32x2 acc = {0.f, 0.f};                                               \
      _Pragma("unroll")                                                     \
      for (int k = 0; k < 27; ++k)                                          \
        acc = pfma(m2[k], w2[c*27 + k], acc);                               \
      f32x2 rr = pfma(acc, tau_s, in2[e]);                                  \
      float gc = g[c];                                                      \
      float aA = fabsf(rr.x) - gc*thwA;                                     \
      float aB = fabsf(rr.y) - gc*thwB;                                     \
      oA[e] = (aA > 0.f) ? copysignf(aA, rr.x) : 0.f;                       \
      oB[e] = (aB > 0.f) ? copysignf(aB, rr.y) : 0.f;                       \
    }                                                                       \
    uint4 qA, qB;                                                           \
    qA.x = bfpack2(oA[0],oA[1]); qA.y = bfpack2(oA[2],oA[3]);               \
    qA.z = bfpack2(oA[4],oA[5]); qA.w = bfpack2(oA[6],oA[7]);               \
    qB.x = bfpack2(oB[0],oB[1]); qB.y = bfpack2(oB[2],oB[3]);               \
    qB.z = bfpack2(oB[4],oB[5]); qB.w = bfpack2(oB[6],oB[7]);               \
    Mh[(size_t)(J)*NVOX + voxA]      = qA;                                  \
    Mh[(size_t)(J)*NVOX + voxA + 16] = qB;                                  \
  }

  ZJ(0)
  ZJ(1)
  ZJ(2)
  ZJ(3)
  #undef ZJ
}

extern "C" void kernel_launch(void* const* d_in, const int* in_sizes, int n_in,
                              void* d_out, int out_size, void* d_ws, size_t ws_size,
                              hipStream_t stream)
{
  const float* X   = (const float*)d_in[0];
  const float* U0  = (const float*)d_in[1];
  const float* V0  = (const float*)d_in[2];
  const float* M   = (const float*)d_in[3];
  const float* wM  = (const float*)d_in[4];
  const float* w0  = (const float*)d_in[5];
  const float* b0  = (const float*)d_in[6];
  const float* w1  = (const float*)d_in[7];
  const float* w2  = (const float*)d_in[8];
  const float* w4  = (const float*)d_in[9];
  const float* tau = (const float*)d_in[10];
  const float* ms  = (const float*)d_in[11];
  const float* g   = (const float*)d_in[12];
  const float* th  = (const float*)d_in[13];
  const float* g2  = (const float*)d_in[14];
  const float* ul  = (const float*)d_in[15];
  const float* vl  = (const float*)d_in[16];

  // ws layout (Mh flanked by live ws memory; conv kernels may stray up to
  // 16B before/after the Mh planes at edges — masked lanes, reads stay
  // inside ws):
  //   c1m fp32 8MB | Mh 4 planes bf16 134.2MB | bg2h 4MB |
  //   Ua 64KB | Va 512B | Gp 256KB | u1p 2KB | g2p 2KB
  float*    c1m  = (float*)d_ws;
  uint4*    Mh   = (uint4*)((char*)d_ws + (size_t)NVOX*4);
  ushort_t* bg2h = (ushort_t*)((char*)Mh + (size_t)NVOX*64);
  float*    Ua   = (float*)((char*)bg2h + (size_t)NVOX*2);
  float*    Va   = Ua + 16384;
  float*    Gp   = Va + 128;         // 4*16384
  float*    u1p  = Gp + 65536;       // 4*128
  float*    g2p  = u1p + 512;        // 4*128

  float* out_f  = (float*)d_out;
  f4*    outX   = (f4*)d_out;                       // X at offset 0
  float* outU   = out_f + NVOX;                     // U after X
  float* outV   = outU + 16384;                     // V after U
  float* outM   = outV + 128;                       // M_out last

  k_convM <<<dim3(4,32,32), 256, 0, stream>>>(M, wM, Mh, X, outX);
  k_conv_fused<0><<<dim3(8,32,4), 256, 0, stream>>>(Mh, w0, w1, b0, bg2h, c1m);

  k_G       <<<dim3(128,4), 256, 0, stream>>>(X, bg2h, U0, V0, Gp);
  k_dotT<0> <<<dim3(128,4), 256, 0, stream>>>(X, bg2h, U0, V0, U0, u1p);
  k_dotT<1> <<<dim3(128,4), 256, 0, stream>>>(X, bg2h, U0, V0, Gp, g2p);
  k_final   <<<1, 256, 0, stream>>>(U0, V0, Gp, u1p, g2p, ul, vl,
                                    Ua, Va, outU, outV);

  k_z    <<<dim3(4,32,32), 256, 0, stream>>>(X, c1m, Ua, Va, w2, Mh,
                                             tau, g, g2, th);
  k_conv_fused<1><<<dim3(8,32,4), 256, 0, stream>>>(Mh, w4, w4, ms, nullptr, outM);
}